// Round 1
// 556.041 us; speedup vs baseline: 1.0369x; 1.0369x over previous
//
#include <hip/hip_runtime.h>
#include <hip/hip_bf16.h>
#include <math.h>

typedef __attribute__((ext_vector_type(8))) short short8;
typedef __attribute__((ext_vector_type(4))) float f32x4;

#define MFMA_BF16 __builtin_amdgcn_mfma_f32_16x16x32_bf16

__device__ __forceinline__ ushort f2bf(float f) {
  union { __hip_bfloat16 h; ushort u; } c;
  c.h = __float2bfloat16(f);
  return c.u;
}
// round-half-up bf16 pack (positive normal floats): cheap
__device__ __forceinline__ uint pack_bf16_ru(float a, float b) {
  uint ua = __builtin_bit_cast(uint, a) + 0x8000u;
  uint ub = __builtin_bit_cast(uint, b) + 0x8000u;
  return (ua >> 16) | (ub & 0xffff0000u);
}
__device__ __forceinline__ void async_cp16(const ushort* g, ushort* l) {
  __builtin_amdgcn_global_load_lds(
      (const __attribute__((address_space(1))) void*)g,
      (__attribute__((address_space(3))) void*)l, 16, 0, 0);
}

// ------------- fused weight fp32->bf16 conversion + bias concat (one launch) -------------
__global__ __launch_bounds__(256) void conv_all(
    const float* __restrict__ Wq, const float* __restrict__ Wk,
    const float* __restrict__ Wv, const float* __restrict__ Wo,
    const float* __restrict__ W1, const float* __restrict__ W2,
    const float* __restrict__ bq, const float* __restrict__ bk,
    const float* __restrict__ bv,
    ushort* __restrict__ wqkv, ushort* __restrict__ wo,
    ushort* __restrict__ w1, ushort* __restrict__ w2,
    float* __restrict__ bqkv) {
  int i = blockIdx.x * 256 + threadIdx.x;   // float4 index
  if (i < 3145728) {
    const float* src; ushort* dst; int off;
    if (i < 786432)        { // Wq|Wk|Wv -> concatenated wqkv [3072,1024]
      dst = wqkv; off = i;
      if (i < 262144)      src = Wq + (size_t)i * 4;
      else if (i < 524288) src = Wk + (size_t)(i - 262144) * 4;
      else                 src = Wv + (size_t)(i - 524288) * 4;
    } else if (i < 1048576) { dst = wo; off = i - 786432;  src = Wo + (size_t)off * 4; }
    else if (i < 2097152)   { dst = w1; off = i - 1048576; src = W1 + (size_t)off * 4; }
    else                    { dst = w2; off = i - 2097152; src = W2 + (size_t)off * 4; }
    float4 v = *(const float4*)src;
    ushort4 o;
    o.x = f2bf(v.x); o.y = f2bf(v.y); o.z = f2bf(v.z); o.w = f2bf(v.w);
    ((ushort4*)dst)[off] = o;
  } else if (i < 3146496) {  // biases: 3 x 256 float4
    int off = i - 3145728;
    const float* src;
    if (off < 256)      src = bq + (size_t)off * 4;
    else if (off < 512) src = bk + (size_t)(off - 256) * 4;
    else                src = bv + (size_t)(off - 512) * 4;
    ((float4*)bqkv)[off] = *(const float4*)src;
  }
}

// ---------------- layernorm: one block per 1024-float row -> bf16 ----------------
__global__ __launch_bounds__(256) void ln_kernel(const float* __restrict__ x,
    const float* __restrict__ g, const float* __restrict__ b,
    ushort* __restrict__ out) {
  const int row = blockIdx.x, t = threadIdx.x;
  float4 v = ((const float4*)(x + (size_t)row * 1024))[t];
  float s  = v.x + v.y + v.z + v.w;
  float ss = v.x*v.x + v.y*v.y + v.z*v.z + v.w*v.w;
  #pragma unroll
  for (int off = 32; off >= 1; off >>= 1) {
    s  += __shfl_xor(s, off);
    ss += __shfl_xor(ss, off);
  }
  __shared__ float red[8];
  int wv = t >> 6, ln = t & 63;
  if (ln == 0) { red[wv] = s; red[4 + wv] = ss; }
  __syncthreads();
  float S  = red[0] + red[1] + red[2] + red[3];
  float SS = red[4] + red[5] + red[6] + red[7];
  float mu  = S * (1.0f/1024.0f);
  float var = SS * (1.0f/1024.0f) - mu*mu;
  float rs  = rsqrtf(var + 1e-6f);
  float4 gv = ((const float4*)g)[t];
  float4 bv = ((const float4*)b)[t];
  ushort4 o;
  o.x = f2bf((v.x-mu)*rs*gv.x + bv.x);
  o.y = f2bf((v.y-mu)*rs*gv.y + bv.y);
  o.z = f2bf((v.z-mu)*rs*gv.z + bv.z);
  o.w = f2bf((v.w-mu)*rs*gv.w + bv.w);
  ((ushort4*)(out + (size_t)row*1024))[t] = o;
}

// ---------------- 128x128 tiled bf16 GEMM, BK=64: C[m,n] = sum_k A[m,k]*Bw[n,k] ----------
enum { EPI_QK = 0, EPI_VT = 1, EPI_WO = 2, EPI_GELU = 3, EPI_OUT = 4 };

template <int EPI>
__global__ __launch_bounds__(256) void gemm_kernel(const ushort* __restrict__ A,
    const ushort* __restrict__ Bw, const float* __restrict__ bias,
    const float* __restrict__ res, void* __restrict__ outp,
    void* __restrict__ outp2, int K, int N, float scale) {
  __shared__ ushort As[2][128 * 32];
  __shared__ ushort Bs[2][128 * 32];
  const int t = threadIdx.x;
  const int m0 = blockIdx.x * 128, n0 = blockIdx.y * 128;
  const int lane = t & 63, wave = t >> 6;
  const int col = lane & 15, quad = lane >> 4;
  const int wrow = (wave >> 1) * 64, wcol = (wave & 1) * 64;

  f32x4 acc[4][4];
  #pragma unroll
  for (int i = 0; i < 4; i++)
    #pragma unroll
    for (int j = 0; j < 4; j++)
      acc[i][j] = (f32x4){0.f, 0.f, 0.f, 0.f};

  const int lrow = lane >> 2, lcol = (lane & 3) * 8;
  const ushort* Ag = A  + (size_t)(m0 + wave * 32 + lrow) * K + lcol;
  const ushort* Bg = Bw + (size_t)(n0 + wave * 32 + lrow) * K + lcol;
  const int ldso = (wave * 32) * 32;

  for (int k0 = 0; k0 < K; k0 += 64) {
    __syncthreads();
    #pragma unroll
    for (int c = 0; c < 2; c++) {
      async_cp16(Ag + k0 + c * 32,                  &As[c][ldso]);
      async_cp16(Ag + (size_t)16 * K + k0 + c * 32, &As[c][ldso + 16 * 32]);
      async_cp16(Bg + k0 + c * 32,                  &Bs[c][ldso]);
      async_cp16(Bg + (size_t)16 * K + k0 + c * 32, &Bs[c][ldso + 16 * 32]);
    }
    __syncthreads();
    #pragma unroll
    for (int c = 0; c < 2; c++) {
      short8 af[4], bf[4];
      #pragma unroll
      for (int tm = 0; tm < 4; tm++)
        af[tm] = *(const short8*)&As[c][(wrow + tm * 16 + col) * 32 + quad * 8];
      #pragma unroll
      for (int tn = 0; tn < 4; tn++)
        bf[tn] = *(const short8*)&Bs[c][(wcol + tn * 16 + col) * 32 + quad * 8];
      #pragma unroll
      for (int tm = 0; tm < 4; tm++)
        #pragma unroll
        for (int tn = 0; tn < 4; tn++)
          acc[tm][tn] = MFMA_BF16(af[tm], bf[tn], acc[tm][tn], 0, 0, 0);
    }
  }

  #pragma unroll
  for (int tm = 0; tm < 4; tm++) {
    #pragma unroll
    for (int tn = 0; tn < 4; tn++) {
      const int n = n0 + wcol + tn * 16 + col;
      const float bn = (EPI == EPI_VT) ? 0.f : bias[n];
      #pragma unroll
      for (int r = 0; r < 4; r++) {
        const int m = m0 + wrow + tm * 16 + quad * 4 + r;
        float v = acc[tm][tn][r] + bn;
        if (EPI == EPI_QK) {
          // n in [0,2048): 0..1023 -> Q (scaled), else K
          int nl = n & 1023, h = nl >> 6, hd = nl & 63;
          int bb = m >> 11, s2 = m & 2047;
          if (n < 1024)
            ((ushort*)outp)[(((size_t)(bb * 16 + h) * 2048 + s2) * 64) + hd] = f2bf(v * scale);
          else
            ((ushort*)outp2)[(((size_t)(bb * 16 + h) * 2048 + s2) * 64) + hd] = f2bf(v);
        } else if (EPI == EPI_VT) {
          // A=Wv, Bw=xn: m = v-dim, n = token. bias indexed by m.
          float vv = v + bias[m];
          int h = m >> 6, hd = m & 63, bb = n >> 11, s2 = n & 2047;
          ((ushort*)outp)[((size_t)((bb * 16 + h) * 64 + hd)) * 2048 + s2] = f2bf(vv);
        } else if (EPI == EPI_GELU) {
          float u = v * 0.7978845608028654f * (1.0f + 0.044715f * v * v);
          float e = __builtin_amdgcn_exp2f(u * 2.885390081777927f);  // e^{2u}
          float th = 1.0f - 2.0f * __builtin_amdgcn_rcpf(e + 1.0f);
          ((ushort*)outp)[(size_t)m * N + n] = f2bf(0.5f * v * (1.0f + th));
        } else {  // EPI_WO / EPI_OUT
          ((float*)outp)[(size_t)m * N + n] = v + res[(size_t)m * N + n];
        }
      }
    }
  }
}

// ---------------- flash attention v8: double-buffered K/V + higher occupancy ----------
// Q: [BH,S,64] bf16 PRE-SCALED by log2(e)/8. K: [BH,S,64]. Vt: [BH,64,S].
// 1024 blocks = 64 heads x 16 q-tiles(128); 4 waves, each wave 32 q (2 groups).
// 2-phase pipeline: issue global_load_lds for chunk t+1, compute chunk t, one
// barrier per chunk (compiler drains vmcnt(0) at the barrier -> latency hidden
// under the compute phase).  bh = bx&63 keeps all q-tiles of a head on one XCD.
__global__ __launch_bounds__(256) void attn_kernel(const ushort* __restrict__ Qb,
    const ushort* __restrict__ Kb, const ushort* __restrict__ Vt,
    ushort* __restrict__ ctx) {
  const int lane = threadIdx.x & 63, wave = threadIdx.x >> 6;
  const int col = lane & 15, quad = lane >> 4;
  const int bx = blockIdx.x;
  const int bh = bx & 63;          // XCD = bh % 8 for every q-tile of this head
  const int qt = bx >> 6;          // 0..15
  const int qbase = qt * 128 + wave * 32;
  const ushort* Qh = Qb + (size_t)bh * 2048 * 64;
  const ushort* Kh = Kb + (size_t)bh * 2048 * 64;
  const ushort* Vh = Vt + (size_t)bh * 64 * 2048;

  short8 qa[2][2];
  #pragma unroll
  for (int qg = 0; qg < 2; qg++) {
    const ushort* Qr = Qh + (size_t)(qbase + qg * 16 + col) * 64 + quad * 8;
    qa[qg][0] = *(const short8*)Qr;
    qa[qg][1] = *(const short8*)(Qr + 32);
  }

  f32x4 Ot[2][4];
  float l_part[2];
  #pragma unroll
  for (int qg = 0; qg < 2; qg++) {
    l_part[qg] = 0.f;
    #pragma unroll
    for (int dt = 0; dt < 4; dt++) Ot[qg][dt] = (f32x4){0.f, 0.f, 0.f, 0.f};
  }

  __shared__ ushort Ks[2][2][64 * 32];     // [buf][d-chunk][key*32 + d%32]  16 KB
  __shared__ ushort Vs[2][2][64 * 32];     // [buf][key-half][d*32 + key%32] 16 KB
  __shared__ ushort P_lds[4][2][16][72];   // [wave][qg][q][key 0..63 (+pad)] 18 KB

  // staging addresses (m97 lane mapping: lds dest = base + lane*16B)
  const int lrow = lane >> 2, lcol = (lane & 3) * 8;
  const ushort* Kg = Kh + (size_t)(wave * 16 + lrow) * 64 + lcol;   // + kb*64 (+32 for c1)
  const ushort* Vg = Vh + (size_t)(wave * 16 + lrow) * 2048 + lcol; // + kb (+32 for c1)
  const int so = (wave * 16) * 32;

  // prologue: stage chunk 0 into buf 0
  async_cp16(Kg,      &Ks[0][0][so]);
  async_cp16(Kg + 32, &Ks[0][1][so]);
  async_cp16(Vg,      &Vs[0][0][so]);
  async_cp16(Vg + 32, &Vs[0][1][so]);
  __syncthreads();

  int cur = 0;
  for (int kb = 0; kb < 2048; kb += 64) {
    // issue next chunk's stage into the other buffer (in flight across compute)
    if (kb + 64 < 2048) {
      const int nxt = cur ^ 1;
      async_cp16(Kg + (size_t)(kb + 64) * 64,      &Ks[nxt][0][so]);
      async_cp16(Kg + (size_t)(kb + 64) * 64 + 32, &Ks[nxt][1][so]);
      async_cp16(Vg + (kb + 64),                   &Vs[nxt][0][so]);
      async_cp16(Vg + (kb + 64) + 32,              &Vs[nxt][1][so]);
    }

    // fragments from LDS (shared across the 2 q-groups)
    short8 kf[4][2], vf[4][2];
    #pragma unroll
    for (int kt = 0; kt < 4; kt++)
      #pragma unroll
      for (int c = 0; c < 2; c++)
        kf[kt][c] = *(const short8*)&Ks[cur][c][(kt * 16 + col) * 32 + quad * 8];
    #pragma unroll
    for (int dt = 0; dt < 4; dt++)
      #pragma unroll
      for (int c = 0; c < 2; c++)
        vf[dt][c] = *(const short8*)&Vs[cur][c][(dt * 16 + col) * 32 + quad * 8];

    #pragma unroll
    for (int qg = 0; qg < 2; qg++) {
      f32x4 s[4];
      __builtin_amdgcn_s_setprio(1);
      #pragma unroll
      for (int kt = 0; kt < 4; kt++) {
        s[kt] = (f32x4){0.f, 0.f, 0.f, 0.f};
        s[kt] = MFMA_BF16(kf[kt][0], qa[qg][0], s[kt], 0, 0, 0);
        s[kt] = MFMA_BF16(kf[kt][1], qa[qg][1], s[kt], 0, 0, 0);
      }
      __builtin_amdgcn_s_setprio(0);
      ushort(*P)[72] = P_lds[wave][qg];
      #pragma unroll
      for (int kt = 0; kt < 4; kt++) {
        float p0 = __builtin_amdgcn_exp2f(s[kt][0]);
        float p1 = __builtin_amdgcn_exp2f(s[kt][1]);
        float p2 = __builtin_amdgcn_exp2f(s[kt][2]);
        float p3 = __builtin_amdgcn_exp2f(s[kt][3]);
        l_part[qg] += (p0 + p1) + (p2 + p3);
        uint2 pk;
        pk.x = pack_bf16_ru(p0, p1);
        pk.y = pack_bf16_ru(p2, p3);
        *(uint2*)&P[col][kt * 16 + quad * 4] = pk;
      }
    }
    #pragma unroll
    for (int qg = 0; qg < 2; qg++) {
      #pragma unroll
      for (int c = 0; c < 2; c++) {
        short8 pf = *(const short8*)&P_lds[wave][qg][col][c * 32 + quad * 8];
        __builtin_amdgcn_s_setprio(1);
        #pragma unroll
        for (int dt = 0; dt < 4; dt++)
          Ot[qg][dt] = MFMA_BF16(vf[dt][c], pf, Ot[qg][dt], 0, 0, 0);
        __builtin_amdgcn_s_setprio(0);
      }
    }
    // barrier (compiler drains vmcnt(0) here): next-chunk stage has landed and
    // every wave is done reading buf[cur] before it gets overwritten next iter.
    __syncthreads();
    cur ^= 1;
  }

  const int bb = bh >> 4, h = bh & 15;
  #pragma unroll
  for (int qg = 0; qg < 2; qg++) {
    float l = l_part[qg];
    l += __shfl_xor(l, 16);
    l += __shfl_xor(l, 32);
    float inv = __builtin_amdgcn_rcpf(l);
    const int q = qbase + qg * 16 + col;
    size_t base = ((size_t)(bb * 2048 + q)) * 1024 + h * 64;
    #pragma unroll
    for (int dt = 0; dt < 4; dt++) {
      ushort4 o;
      o.x = f2bf(Ot[qg][dt][0] * inv);
      o.y = f2bf(Ot[qg][dt][1] * inv);
      o.z = f2bf(Ot[qg][dt][2] * inv);
      o.w = f2bf(Ot[qg][dt][3] * inv);
      *(ushort4*)&ctx[base + dt * 16 + quad * 4] = o;
    }
  }
}

// ---------------- host ----------------
extern "C" void kernel_launch(void* const* d_in, const int* in_sizes, int n_in,
                              void* d_out, int out_size, void* d_ws, size_t ws_size,
                              hipStream_t stream) {
  const float* x     = (const float*)d_in[0];
  const float* Wq    = (const float*)d_in[1];
  const float* bq    = (const float*)d_in[2];
  const float* Wk    = (const float*)d_in[3];
  const float* bk    = (const float*)d_in[4];
  const float* Wv    = (const float*)d_in[5];
  const float* bv    = (const float*)d_in[6];
  const float* Wo    = (const float*)d_in[7];
  const float* bo    = (const float*)d_in[8];
  const float* W1    = (const float*)d_in[9];
  const float* b1    = (const float*)d_in[10];
  const float* W2    = (const float*)d_in[11];
  const float* b2    = (const float*)d_in[12];
  const float* ln1_g = (const float*)d_in[13];
  const float* ln1_b = (const float*)d_in[14];
  const float* ln2_g = (const float*)d_in[15];
  const float* ln2_b = (const float*)d_in[16];

  const size_t MB = 1ull << 20;
  char* ws = (char*)d_ws;
  ushort* Wqkv_b = (ushort*)(ws + 0 * MB);    // 6 MB  [3072,1024] (Q|K|V)
  ushort* Wo_b   = (ushort*)(ws + 6 * MB);    // 2 MB
  ushort* W1_b   = (ushort*)(ws + 8 * MB);    // 8 MB
  ushort* W2_b   = (ushort*)(ws + 16 * MB);   // 8 MB
  ushort* xn1    = (ushort*)(ws + 24 * MB);   // 16 MB
  ushort* Qb     = (ushort*)(ws + 40 * MB);   // 16 MB
  ushort* Kb     = (ushort*)(ws + 56 * MB);   // 16 MB
  ushort* Vt     = (ushort*)(ws + 72 * MB);   // 16 MB
  ushort* ctxb   = (ushort*)(ws + 88 * MB);   // 16 MB
  float*  x2     = (float*)(ws + 104 * MB);   // 32 MB
  ushort* xn2    = (ushort*)(ws + 136 * MB);  // 16 MB
  ushort* y1     = (ushort*)(ws + 152 * MB);  // 64 MB -> end 216 MB
  // bqkv aliases start of y1 (lifetime-disjoint: consumed before GELU GEMM writes y1)
  float*  bqkv   = (float*)(ws + 152 * MB);

  conv_all<<<12291, 256, 0, stream>>>(Wq, Wk, Wv, Wo, W1, W2, bq, bk, bv,
                                      Wqkv_b, Wo_b, W1_b, W2_b, bqkv);

  ln_kernel<<<8192, 256, 0, stream>>>(x, ln1_g, ln1_b, xn1);

  const float cs = 0.125f * 1.4426950408889634f;  // log2(e)/sqrt(64), folded into Q
  // Q|K projections (N=2048)
  gemm_kernel<EPI_QK><<<dim3(64, 16), 256, 0, stream>>>(
      xn1, Wqkv_b, bqkv, nullptr, Qb, Kb, 1024, 2048, cs);
  // V^T projection: A = Wv (rows = v-dim), B = xn (rows = tokens) -> C[vdim, token]
  gemm_kernel<EPI_VT><<<dim3(8, 64), 256, 0, stream>>>(
      Wqkv_b + (size_t)2048 * 1024, xn1, bqkv + 2048, nullptr, Vt, nullptr,
      1024, 8192, 1.0f);

  attn_kernel<<<1024, 256, 0, stream>>>(Qb, Kb, Vt, ctxb);

  gemm_kernel<EPI_WO><<<dim3(64, 8), 256, 0, stream>>>(
      ctxb, Wo_b, bo, x, x2, nullptr, 1024, 1024, 1.0f);

  ln_kernel<<<8192, 256, 0, stream>>>(x2, ln2_g, ln2_b, xn2);

  gemm_kernel<EPI_GELU><<<dim3(64, 32), 256, 0, stream>>>(
      xn2, W1_b, b1, nullptr, y1, nullptr, 1024, 4096, 1.0f);
  gemm_kernel<EPI_OUT><<<dim3(64, 8), 256, 0, stream>>>(
      y1, W2_b, b2, x2, d_out, nullptr, 4096, 1024, 1.0f);
}

// Round 2
// 548.742 us; speedup vs baseline: 1.0507x; 1.0133x over previous
//
#include <hip/hip_runtime.h>
#include <hip/hip_bf16.h>
#include <math.h>

typedef __attribute__((ext_vector_type(8))) short short8;
typedef __attribute__((ext_vector_type(4))) float f32x4;

#define MFMA_BF16 __builtin_amdgcn_mfma_f32_16x16x32_bf16

__device__ __forceinline__ ushort f2bf(float f) {
  union { __hip_bfloat16 h; ushort u; } c;
  c.h = __float2bfloat16(f);
  return c.u;
}
// round-half-up bf16 pack (positive normal floats): cheap
__device__ __forceinline__ uint pack_bf16_ru(float a, float b) {
  uint ua = __builtin_bit_cast(uint, a) + 0x8000u;
  uint ub = __builtin_bit_cast(uint, b) + 0x8000u;
  return (ua >> 16) | (ub & 0xffff0000u);
}
__device__ __forceinline__ void async_cp16(const ushort* g, ushort* l) {
  __builtin_amdgcn_global_load_lds(
      (const __attribute__((address_space(1))) void*)g,
      (__attribute__((address_space(3))) void*)l, 16, 0, 0);
}

// ------------- fused weight fp32->bf16 conversion + bias concat (one launch) -------------
__global__ __launch_bounds__(256) void conv_all(
    const float* __restrict__ Wq, const float* __restrict__ Wk,
    const float* __restrict__ Wv, const float* __restrict__ Wo,
    const float* __restrict__ W1, const float* __restrict__ W2,
    const float* __restrict__ bq, const float* __restrict__ bk,
    const float* __restrict__ bv,
    ushort* __restrict__ wqkv, ushort* __restrict__ wo,
    ushort* __restrict__ w1, ushort* __restrict__ w2,
    float* __restrict__ bqkv) {
  int i = blockIdx.x * 256 + threadIdx.x;   // float4 index
  if (i < 3145728) {
    const float* src; ushort* dst; int off;
    if (i < 786432)        { // Wq|Wk|Wv -> concatenated wqkv [3072,1024]
      dst = wqkv; off = i;
      if (i < 262144)      src = Wq + (size_t)i * 4;
      else if (i < 524288) src = Wk + (size_t)(i - 262144) * 4;
      else                 src = Wv + (size_t)(i - 524288) * 4;
    } else if (i < 1048576) { dst = wo; off = i - 786432;  src = Wo + (size_t)off * 4; }
    else if (i < 2097152)   { dst = w1; off = i - 1048576; src = W1 + (size_t)off * 4; }
    else                    { dst = w2; off = i - 2097152; src = W2 + (size_t)off * 4; }
    float4 v = *(const float4*)src;
    ushort4 o;
    o.x = f2bf(v.x); o.y = f2bf(v.y); o.z = f2bf(v.z); o.w = f2bf(v.w);
    ((ushort4*)dst)[off] = o;
  } else if (i < 3146496) {  // biases: 3 x 256 float4
    int off = i - 3145728;
    const float* src;
    if (off < 256)      src = bq + (size_t)off * 4;
    else if (off < 512) src = bk + (size_t)(off - 256) * 4;
    else                src = bv + (size_t)(off - 512) * 4;
    ((float4*)bqkv)[off] = *(const float4*)src;
  }
}

// ---------------- layernorm: one block per 1024-float row -> bf16 ----------------
__global__ __launch_bounds__(256) void ln_kernel(const float* __restrict__ x,
    const float* __restrict__ g, const float* __restrict__ b,
    ushort* __restrict__ out) {
  const int row = blockIdx.x, t = threadIdx.x;
  float4 v = ((const float4*)(x + (size_t)row * 1024))[t];
  float s  = v.x + v.y + v.z + v.w;
  float ss = v.x*v.x + v.y*v.y + v.z*v.z + v.w*v.w;
  #pragma unroll
  for (int off = 32; off >= 1; off >>= 1) {
    s  += __shfl_xor(s, off);
    ss += __shfl_xor(ss, off);
  }
  __shared__ float red[8];
  int wv = t >> 6, ln = t & 63;
  if (ln == 0) { red[wv] = s; red[4 + wv] = ss; }
  __syncthreads();
  float S  = red[0] + red[1] + red[2] + red[3];
  float SS = red[4] + red[5] + red[6] + red[7];
  float mu  = S * (1.0f/1024.0f);
  float var = SS * (1.0f/1024.0f) - mu*mu;
  float rs  = rsqrtf(var + 1e-6f);
  float4 gv = ((const float4*)g)[t];
  float4 bv = ((const float4*)b)[t];
  ushort4 o;
  o.x = f2bf((v.x-mu)*rs*gv.x + bv.x);
  o.y = f2bf((v.y-mu)*rs*gv.y + bv.y);
  o.z = f2bf((v.z-mu)*rs*gv.z + bv.z);
  o.w = f2bf((v.w-mu)*rs*gv.w + bv.w);
  ((ushort4*)(out + (size_t)row*1024))[t] = o;
}

// ---------------- 128x128 tiled bf16 GEMM, BK=64: C[m,n] = sum_k A[m,k]*Bw[n,k] ----------
enum { EPI_QK = 0, EPI_VT = 1, EPI_WO = 2, EPI_GELU = 3, EPI_OUT = 4 };

template <int EPI>
__global__ __launch_bounds__(256) void gemm_kernel(const ushort* __restrict__ A,
    const ushort* __restrict__ Bw, const float* __restrict__ bias,
    const float* __restrict__ res, void* __restrict__ outp,
    void* __restrict__ outp2, int K, int N, float scale) {
  __shared__ ushort As[2][128 * 32];
  __shared__ ushort Bs[2][128 * 32];
  const int t = threadIdx.x;
  const int m0 = blockIdx.x * 128, n0 = blockIdx.y * 128;
  const int lane = t & 63, wave = t >> 6;
  const int col = lane & 15, quad = lane >> 4;
  const int wrow = (wave >> 1) * 64, wcol = (wave & 1) * 64;

  f32x4 acc[4][4];
  #pragma unroll
  for (int i = 0; i < 4; i++)
    #pragma unroll
    for (int j = 0; j < 4; j++)
      acc[i][j] = (f32x4){0.f, 0.f, 0.f, 0.f};

  const int lrow = lane >> 2, lcol = (lane & 3) * 8;
  const ushort* Ag = A  + (size_t)(m0 + wave * 32 + lrow) * K + lcol;
  const ushort* Bg = Bw + (size_t)(n0 + wave * 32 + lrow) * K + lcol;
  const int ldso = (wave * 32) * 32;

  for (int k0 = 0; k0 < K; k0 += 64) {
    __syncthreads();
    #pragma unroll
    for (int c = 0; c < 2; c++) {
      async_cp16(Ag + k0 + c * 32,                  &As[c][ldso]);
      async_cp16(Ag + (size_t)16 * K + k0 + c * 32, &As[c][ldso + 16 * 32]);
      async_cp16(Bg + k0 + c * 32,                  &Bs[c][ldso]);
      async_cp16(Bg + (size_t)16 * K + k0 + c * 32, &Bs[c][ldso + 16 * 32]);
    }
    __syncthreads();
    #pragma unroll
    for (int c = 0; c < 2; c++) {
      short8 af[4], bf[4];
      #pragma unroll
      for (int tm = 0; tm < 4; tm++)
        af[tm] = *(const short8*)&As[c][(wrow + tm * 16 + col) * 32 + quad * 8];
      #pragma unroll
      for (int tn = 0; tn < 4; tn++)
        bf[tn] = *(const short8*)&Bs[c][(wcol + tn * 16 + col) * 32 + quad * 8];
      #pragma unroll
      for (int tm = 0; tm < 4; tm++)
        #pragma unroll
        for (int tn = 0; tn < 4; tn++)
          acc[tm][tn] = MFMA_BF16(af[tm], bf[tn], acc[tm][tn], 0, 0, 0);
    }
  }

  #pragma unroll
  for (int tm = 0; tm < 4; tm++) {
    #pragma unroll
    for (int tn = 0; tn < 4; tn++) {
      const int n = n0 + wcol + tn * 16 + col;
      const float bn = (EPI == EPI_VT) ? 0.f : bias[n];
      #pragma unroll
      for (int r = 0; r < 4; r++) {
        const int m = m0 + wrow + tm * 16 + quad * 4 + r;
        float v = acc[tm][tn][r] + bn;
        if (EPI == EPI_QK) {
          // n in [0,2048): 0..1023 -> Q (scaled), else K
          int nl = n & 1023, h = nl >> 6, hd = nl & 63;
          int bb = m >> 11, s2 = m & 2047;
          if (n < 1024)
            ((ushort*)outp)[(((size_t)(bb * 16 + h) * 2048 + s2) * 64) + hd] = f2bf(v * scale);
          else
            ((ushort*)outp2)[(((size_t)(bb * 16 + h) * 2048 + s2) * 64) + hd] = f2bf(v);
        } else if (EPI == EPI_VT) {
          // A=Wv, Bw=xn: m = v-dim, n = token. bias indexed by m.
          float vv = v + bias[m];
          int h = m >> 6, hd = m & 63, bb = n >> 11, s2 = n & 2047;
          ((ushort*)outp)[((size_t)((bb * 16 + h) * 64 + hd)) * 2048 + s2] = f2bf(vv);
        } else if (EPI == EPI_GELU) {
          float u = v * 0.7978845608028654f * (1.0f + 0.044715f * v * v);
          float e = __builtin_amdgcn_exp2f(u * 2.885390081777927f);  // e^{2u}
          float th = 1.0f - 2.0f * __builtin_amdgcn_rcpf(e + 1.0f);
          ((ushort*)outp)[(size_t)m * N + n] = f2bf(0.5f * v * (1.0f + th));
        } else {  // EPI_WO / EPI_OUT
          ((float*)outp)[(size_t)m * N + n] = v + res[(size_t)m * N + n];
        }
      }
    }
  }
}

// ---------------- flash attention v9: conflict-free LDS (XOR swizzle both sides) -------
// Q: [BH,S,64] bf16 PRE-SCALED by log2(e)/8. K: [BH,S,64]. Vt: [BH,64,S].
// 1024 blocks = 64 heads x 16 q-tiles(128); 4 waves, each wave 32 q (2 groups).
// K/V staged via global_load_lds with PRE-SWIZZLED GLOBAL SOURCE (m173/m201 pattern):
//   LDS dest stays linear; global 16B-chunk j within each 64B row-half is read from
//   j ^ ((row>>1)&3). Fragment reads apply the same XOR -> even bank distribution
//   (8 lanes per 4-bank group = minimum cycles, conflict-free).
// P_lds: 64-ushort rows (8 x 16B chunks), chunk ^= (col&7) on write AND read.
__global__ __launch_bounds__(256) void attn_kernel(const ushort* __restrict__ Qb,
    const ushort* __restrict__ Kb, const ushort* __restrict__ Vt,
    ushort* __restrict__ ctx) {
  const int lane = threadIdx.x & 63, wave = threadIdx.x >> 6;
  const int col = lane & 15, quad = lane >> 4;
  const int bx = blockIdx.x;
  const int bh = bx & 63;          // XCD = bh % 8 for every q-tile of this head
  const int qt = bx >> 6;          // 0..15
  const int qbase = qt * 128 + wave * 32;
  const ushort* Qh = Qb + (size_t)bh * 2048 * 64;
  const ushort* Kh = Kb + (size_t)bh * 2048 * 64;
  const ushort* Vh = Vt + (size_t)bh * 64 * 2048;

  short8 qa[2][2];
  #pragma unroll
  for (int qg = 0; qg < 2; qg++) {
    const ushort* Qr = Qh + (size_t)(qbase + qg * 16 + col) * 64 + quad * 8;
    qa[qg][0] = *(const short8*)Qr;
    qa[qg][1] = *(const short8*)(Qr + 32);
  }

  f32x4 Ot[2][4];
  float l_part[2];
  #pragma unroll
  for (int qg = 0; qg < 2; qg++) {
    l_part[qg] = 0.f;
    #pragma unroll
    for (int dt = 0; dt < 4; dt++) Ot[qg][dt] = (f32x4){0.f, 0.f, 0.f, 0.f};
  }

  __shared__ ushort Ks[2][2][64 * 32];     // [buf][d-half][key*32 + swz-chunk] 16 KB
  __shared__ ushort Vs[2][2][64 * 32];     // [buf][key-half][d*32 + swz-chunk] 16 KB
  __shared__ ushort P_lds[4][2][16][64];   // [wave][qg][q][8 x 16B chunks, swz] 16 KB

  // staging addresses (lds dest = base + lane*16B, LINEAR; source chunk pre-swizzled)
  const int lrow = lane >> 2;
  const int srow = wave * 16 + lrow;                       // row this lane stages
  const int lcol = ((lane & 3) ^ ((srow >> 1) & 3)) * 8;   // swizzled 16B chunk in 64B half
  const ushort* Kg = Kh + (size_t)srow * 64 + lcol;        // + kb*64 (+32 for half 1)
  const ushort* Vg = Vh + (size_t)srow * 2048 + lcol;      // + kb   (+32 for half 1)
  const int so = (wave * 16) * 32;

  const int kvswz = (col >> 1) & 3;   // fragment-read XOR (rows kt*16+col: (row>>1)&3)
  const int pswz = col & 7;           // P chunk XOR

  // prologue: stage chunk 0 into buf 0
  async_cp16(Kg,      &Ks[0][0][so]);
  async_cp16(Kg + 32, &Ks[0][1][so]);
  async_cp16(Vg,      &Vs[0][0][so]);
  async_cp16(Vg + 32, &Vs[0][1][so]);
  __syncthreads();

  int cur = 0;
  for (int kb = 0; kb < 2048; kb += 64) {
    // issue next chunk's stage into the other buffer (in flight across compute)
    if (kb + 64 < 2048) {
      const int nxt = cur ^ 1;
      async_cp16(Kg + (size_t)(kb + 64) * 64,      &Ks[nxt][0][so]);
      async_cp16(Kg + (size_t)(kb + 64) * 64 + 32, &Ks[nxt][1][so]);
      async_cp16(Vg + (kb + 64),                   &Vs[nxt][0][so]);
      async_cp16(Vg + (kb + 64) + 32,              &Vs[nxt][1][so]);
    }

    // fragments from LDS (shared across the 2 q-groups), swizzled reads
    short8 kf[4][2], vf[4][2];
    #pragma unroll
    for (int kt = 0; kt < 4; kt++)
      #pragma unroll
      for (int c = 0; c < 2; c++)
        kf[kt][c] = *(const short8*)&Ks[cur][c][(kt * 16 + col) * 32 + (quad ^ kvswz) * 8];
    #pragma unroll
    for (int dt = 0; dt < 4; dt++)
      #pragma unroll
      for (int c = 0; c < 2; c++)
        vf[dt][c] = *(const short8*)&Vs[cur][c][(dt * 16 + col) * 32 + (quad ^ kvswz) * 8];

    #pragma unroll
    for (int qg = 0; qg < 2; qg++) {
      f32x4 s[4];
      __builtin_amdgcn_s_setprio(1);
      #pragma unroll
      for (int kt = 0; kt < 4; kt++) {
        s[kt] = (f32x4){0.f, 0.f, 0.f, 0.f};
        s[kt] = MFMA_BF16(kf[kt][0], qa[qg][0], s[kt], 0, 0, 0);
        s[kt] = MFMA_BF16(kf[kt][1], qa[qg][1], s[kt], 0, 0, 0);
      }
      __builtin_amdgcn_s_setprio(0);
      ushort(*P)[64] = P_lds[wave][qg];
      #pragma unroll
      for (int kt = 0; kt < 4; kt++) {
        float p0 = __builtin_amdgcn_exp2f(s[kt][0]);
        float p1 = __builtin_amdgcn_exp2f(s[kt][1]);
        float p2 = __builtin_amdgcn_exp2f(s[kt][2]);
        float p3 = __builtin_amdgcn_exp2f(s[kt][3]);
        l_part[qg] += (p0 + p1) + (p2 + p3);
        uint2 pk;
        pk.x = pack_bf16_ru(p0, p1);
        pk.y = pack_bf16_ru(p2, p3);
        // keys kt*16+quad*4..+3 -> 16B chunk (2kt + quad>>1), half (quad&1); chunk ^= pswz
        *(uint2*)&P[col][(((2 * kt + (quad >> 1)) ^ pswz) * 8) + (quad & 1) * 4] = pk;
      }
    }
    #pragma unroll
    for (int qg = 0; qg < 2; qg++) {
      #pragma unroll
      for (int c = 0; c < 2; c++) {
        // keys c*32+quad*8..+7 -> chunk (4c+quad) ^ pswz
        short8 pf = *(const short8*)&P_lds[wave][qg][col][((4 * c + quad) ^ pswz) * 8];
        __builtin_amdgcn_s_setprio(1);
        #pragma unroll
        for (int dt = 0; dt < 4; dt++)
          Ot[qg][dt] = MFMA_BF16(vf[dt][c], pf, Ot[qg][dt], 0, 0, 0);
        __builtin_amdgcn_s_setprio(0);
      }
    }
    // barrier (compiler drains vmcnt(0) here): next-chunk stage has landed and
    // every wave is done reading buf[cur] before it gets overwritten next iter.
    __syncthreads();
    cur ^= 1;
  }

  const int bb = bh >> 4, h = bh & 15;
  #pragma unroll
  for (int qg = 0; qg < 2; qg++) {
    float l = l_part[qg];
    l += __shfl_xor(l, 16);
    l += __shfl_xor(l, 32);
    float inv = __builtin_amdgcn_rcpf(l);
    const int q = qbase + qg * 16 + col;
    size_t base = ((size_t)(bb * 2048 + q)) * 1024 + h * 64;
    #pragma unroll
    for (int dt = 0; dt < 4; dt++) {
      ushort4 o;
      o.x = f2bf(Ot[qg][dt][0] * inv);
      o.y = f2bf(Ot[qg][dt][1] * inv);
      o.z = f2bf(Ot[qg][dt][2] * inv);
      o.w = f2bf(Ot[qg][dt][3] * inv);
      *(ushort4*)&ctx[base + dt * 16 + quad * 4] = o;
    }
  }
}

// ---------------- host ----------------
extern "C" void kernel_launch(void* const* d_in, const int* in_sizes, int n_in,
                              void* d_out, int out_size, void* d_ws, size_t ws_size,
                              hipStream_t stream) {
  const float* x     = (const float*)d_in[0];
  const float* Wq    = (const float*)d_in[1];
  const float* bq    = (const float*)d_in[2];
  const float* Wk    = (const float*)d_in[3];
  const float* bk    = (const float*)d_in[4];
  const float* Wv    = (const float*)d_in[5];
  const float* bv    = (const float*)d_in[6];
  const float* Wo    = (const float*)d_in[7];
  const float* bo    = (const float*)d_in[8];
  const float* W1    = (const float*)d_in[9];
  const float* b1    = (const float*)d_in[10];
  const float* W2    = (const float*)d_in[11];
  const float* b2    = (const float*)d_in[12];
  const float* ln1_g = (const float*)d_in[13];
  const float* ln1_b = (const float*)d_in[14];
  const float* ln2_g = (const float*)d_in[15];
  const float* ln2_b = (const float*)d_in[16];

  const size_t MB = 1ull << 20;
  char* ws = (char*)d_ws;
  ushort* Wqkv_b = (ushort*)(ws + 0 * MB);    // 6 MB  [3072,1024] (Q|K|V)
  ushort* Wo_b   = (ushort*)(ws + 6 * MB);    // 2 MB
  ushort* W1_b   = (ushort*)(ws + 8 * MB);    // 8 MB
  ushort* W2_b   = (ushort*)(ws + 16 * MB);   // 8 MB
  ushort* xn1    = (ushort*)(ws + 24 * MB);   // 16 MB
  ushort* Qb     = (ushort*)(ws + 40 * MB);   // 16 MB
  ushort* Kb     = (ushort*)(ws + 56 * MB);   // 16 MB
  ushort* Vt     = (ushort*)(ws + 72 * MB);   // 16 MB
  ushort* ctxb   = (ushort*)(ws + 88 * MB);   // 16 MB
  float*  x2     = (float*)(ws + 104 * MB);   // 32 MB
  ushort* xn2    = (ushort*)(ws + 136 * MB);  // 16 MB
  ushort* y1     = (ushort*)(ws + 152 * MB);  // 64 MB -> end 216 MB
  // bqkv aliases start of y1 (lifetime-disjoint: consumed before GELU GEMM writes y1)
  float*  bqkv   = (float*)(ws + 152 * MB);

  conv_all<<<12291, 256, 0, stream>>>(Wq, Wk, Wv, Wo, W1, W2, bq, bk, bv,
                                      Wqkv_b, Wo_b, W1_b, W2_b, bqkv);

  ln_kernel<<<8192, 256, 0, stream>>>(x, ln1_g, ln1_b, xn1);

  const float cs = 0.125f * 1.4426950408889634f;  // log2(e)/sqrt(64), folded into Q
  // Q|K projections (N=2048)
  gemm_kernel<EPI_QK><<<dim3(64, 16), 256, 0, stream>>>(
      xn1, Wqkv_b, bqkv, nullptr, Qb, Kb, 1024, 2048, cs);
  // V^T projection: A = Wv (rows = v-dim), B = xn (rows = tokens) -> C[vdim, token]
  gemm_kernel<EPI_VT><<<dim3(8, 64), 256, 0, stream>>>(
      Wqkv_b + (size_t)2048 * 1024, xn1, bqkv + 2048, nullptr, Vt, nullptr,
      1024, 8192, 1.0f);

  attn_kernel<<<1024, 256, 0, stream>>>(Qb, Kb, Vt, ctxb);

  gemm_kernel<EPI_WO><<<dim3(64, 8), 256, 0, stream>>>(
      ctxb, Wo_b, bo, x, x2, nullptr, 1024, 1024, 1.0f);

  ln_kernel<<<8192, 256, 0, stream>>>(x2, ln2_g, ln2_b, xn2);

  gemm_kernel<EPI_GELU><<<dim3(64, 32), 256, 0, stream>>>(
      xn2, W1_b, b1, nullptr, y1, nullptr, 1024, 4096, 1.0f);
  gemm_kernel<EPI_OUT><<<dim3(64, 8), 256, 0, stream>>>(
      y1, W2_b, b2, x2, d_out, nullptr, 4096, 1024, 1.0f);
}

// Round 3
// 515.250 us; speedup vs baseline: 1.1190x; 1.0650x over previous
//
#include <hip/hip_runtime.h>
#include <hip/hip_bf16.h>
#include <math.h>

typedef __attribute__((ext_vector_type(8))) short short8;
typedef __attribute__((ext_vector_type(4))) float f32x4;

#define MFMA_BF16 __builtin_amdgcn_mfma_f32_16x16x32_bf16

__device__ __forceinline__ ushort f2bf(float f) {
  union { __hip_bfloat16 h; ushort u; } c;
  c.h = __float2bfloat16(f);
  return c.u;
}
__device__ __forceinline__ void async_cp16(const ushort* g, ushort* l) {
  __builtin_amdgcn_global_load_lds(
      (const __attribute__((address_space(1))) void*)g,
      (__attribute__((address_space(3))) void*)l, 16, 0, 0);
}

// ------------- fused weight fp32->bf16 conversion + bias concat (one launch) -------------
__global__ __launch_bounds__(256) void conv_all(
    const float* __restrict__ Wq, const float* __restrict__ Wk,
    const float* __restrict__ Wv, const float* __restrict__ Wo,
    const float* __restrict__ W1, const float* __restrict__ W2,
    const float* __restrict__ bq, const float* __restrict__ bk,
    const float* __restrict__ bv,
    ushort* __restrict__ wqkv, ushort* __restrict__ wo,
    ushort* __restrict__ w1, ushort* __restrict__ w2,
    float* __restrict__ bqkv) {
  int i = blockIdx.x * 256 + threadIdx.x;   // float4 index
  if (i < 3145728) {
    const float* src; ushort* dst; int off;
    if (i < 786432)        { // Wq|Wk|Wv -> concatenated wqkv [3072,1024]
      dst = wqkv; off = i;
      if (i < 262144)      src = Wq + (size_t)i * 4;
      else if (i < 524288) src = Wk + (size_t)(i - 262144) * 4;
      else                 src = Wv + (size_t)(i - 524288) * 4;
    } else if (i < 1048576) { dst = wo; off = i - 786432;  src = Wo + (size_t)off * 4; }
    else if (i < 2097152)   { dst = w1; off = i - 1048576; src = W1 + (size_t)off * 4; }
    else                    { dst = w2; off = i - 2097152; src = W2 + (size_t)off * 4; }
    float4 v = *(const float4*)src;
    ushort4 o;
    o.x = f2bf(v.x); o.y = f2bf(v.y); o.z = f2bf(v.z); o.w = f2bf(v.w);
    ((ushort4*)dst)[off] = o;
  } else if (i < 3146496) {  // biases: 3 x 256 float4
    int off = i - 3145728;
    const float* src;
    if (off < 256)      src = bq + (size_t)off * 4;
    else if (off < 512) src = bk + (size_t)(off - 256) * 4;
    else                src = bv + (size_t)(off - 512) * 4;
    ((float4*)bqkv)[off] = *(const float4*)src;
  }
}

// ---------------- layernorm: one block per 1024-float row -> bf16 ----------------
__global__ __launch_bounds__(256) void ln_kernel(const float* __restrict__ x,
    const float* __restrict__ g, const float* __restrict__ b,
    ushort* __restrict__ out) {
  const int row = blockIdx.x, t = threadIdx.x;
  float4 v = ((const float4*)(x + (size_t)row * 1024))[t];
  float s  = v.x + v.y + v.z + v.w;
  float ss = v.x*v.x + v.y*v.y + v.z*v.z + v.w*v.w;
  #pragma unroll
  for (int off = 32; off >= 1; off >>= 1) {
    s  += __shfl_xor(s, off);
    ss += __shfl_xor(ss, off);
  }
  __shared__ float red[8];
  int wv = t >> 6, ln = t & 63;
  if (ln == 0) { red[wv] = s; red[4 + wv] = ss; }
  __syncthreads();
  float S  = red[0] + red[1] + red[2] + red[3];
  float SS = red[4] + red[5] + red[6] + red[7];
  float mu  = S * (1.0f/1024.0f);
  float var = SS * (1.0f/1024.0f) - mu*mu;
  float rs  = rsqrtf(var + 1e-6f);
  float4 gv = ((const float4*)g)[t];
  float4 bv = ((const float4*)b)[t];
  ushort4 o;
  o.x = f2bf((v.x-mu)*rs*gv.x + bv.x);
  o.y = f2bf((v.y-mu)*rs*gv.y + bv.y);
  o.z = f2bf((v.z-mu)*rs*gv.z + bv.z);
  o.w = f2bf((v.w-mu)*rs*gv.w + bv.w);
  ((ushort4*)(out + (size_t)row*1024))[t] = o;
}

enum { EPI_QK = 0, EPI_VT = 1, EPI_WO = 2, EPI_GELU = 3, EPI_OUT = 4 };

// ---------------- 128x128 tiled bf16 GEMM (2-barrier drain structure) ----------------
// kept for VT / WO / OUT whose shapes under-occupy a 256^2 grid
template <int EPI>
__global__ __launch_bounds__(256) void gemm_kernel(const ushort* __restrict__ A,
    const ushort* __restrict__ Bw, const float* __restrict__ bias,
    const float* __restrict__ res, void* __restrict__ outp,
    void* __restrict__ outp2, int K, int N, float scale) {
  __shared__ ushort As[2][128 * 32];
  __shared__ ushort Bs[2][128 * 32];
  const int t = threadIdx.x;
  const int m0 = blockIdx.x * 128, n0 = blockIdx.y * 128;
  const int lane = t & 63, wave = t >> 6;
  const int col = lane & 15, quad = lane >> 4;
  const int wrow = (wave >> 1) * 64, wcol = (wave & 1) * 64;

  f32x4 acc[4][4];
  #pragma unroll
  for (int i = 0; i < 4; i++)
    #pragma unroll
    for (int j = 0; j < 4; j++)
      acc[i][j] = (f32x4){0.f, 0.f, 0.f, 0.f};

  const int lrow = lane >> 2, lcol = (lane & 3) * 8;
  const ushort* Ag = A  + (size_t)(m0 + wave * 32 + lrow) * K + lcol;
  const ushort* Bg = Bw + (size_t)(n0 + wave * 32 + lrow) * K + lcol;
  const int ldso = (wave * 32) * 32;

  for (int k0 = 0; k0 < K; k0 += 64) {
    __syncthreads();
    #pragma unroll
    for (int c = 0; c < 2; c++) {
      async_cp16(Ag + k0 + c * 32,                  &As[c][ldso]);
      async_cp16(Ag + (size_t)16 * K + k0 + c * 32, &As[c][ldso + 16 * 32]);
      async_cp16(Bg + k0 + c * 32,                  &Bs[c][ldso]);
      async_cp16(Bg + (size_t)16 * K + k0 + c * 32, &Bs[c][ldso + 16 * 32]);
    }
    __syncthreads();
    #pragma unroll
    for (int c = 0; c < 2; c++) {
      short8 af[4], bf[4];
      #pragma unroll
      for (int tm = 0; tm < 4; tm++)
        af[tm] = *(const short8*)&As[c][(wrow + tm * 16 + col) * 32 + quad * 8];
      #pragma unroll
      for (int tn = 0; tn < 4; tn++)
        bf[tn] = *(const short8*)&Bs[c][(wcol + tn * 16 + col) * 32 + quad * 8];
      #pragma unroll
      for (int tm = 0; tm < 4; tm++)
        #pragma unroll
        for (int tn = 0; tn < 4; tn++)
          acc[tm][tn] = MFMA_BF16(af[tm], bf[tn], acc[tm][tn], 0, 0, 0);
    }
  }

  #pragma unroll
  for (int tm = 0; tm < 4; tm++) {
    #pragma unroll
    for (int tn = 0; tn < 4; tn++) {
      const int n = n0 + wcol + tn * 16 + col;
      const float bn = (EPI == EPI_VT) ? 0.f : bias[n];
      #pragma unroll
      for (int r = 0; r < 4; r++) {
        const int m = m0 + wrow + tm * 16 + quad * 4 + r;
        float v = acc[tm][tn][r] + bn;
        if (EPI == EPI_VT) {
          // A=Wv, Bw=xn: m = v-dim, n = token. bias indexed by m.
          float vv = v + bias[m];
          int h = m >> 6, hd = m & 63, bb = n >> 11, s2 = n & 2047;
          ((ushort*)outp)[((size_t)((bb * 16 + h) * 64 + hd)) * 2048 + s2] = f2bf(vv);
        } else if (EPI == EPI_GELU) {
          float u = v * 0.7978845608028654f * (1.0f + 0.044715f * v * v);
          float e = __builtin_amdgcn_exp2f(u * 2.885390081777927f);  // e^{2u}
          float th = 1.0f - 2.0f * __builtin_amdgcn_rcpf(e + 1.0f);
          ((ushort*)outp)[(size_t)m * N + n] = f2bf(0.5f * v * (1.0f + th));
        } else {  // EPI_WO / EPI_OUT
          ((float*)outp)[(size_t)m * N + n] = v + res[(size_t)m * N + n];
        }
      }
    }
  }
}

// ---------------- 256x256 tiled bf16 GEMM, BK=64, 8 waves, counted vmcnt pipeline ------
// T3+T4 structure: stage tile t+1 into buf^1 (8 global_load_lds), s_waitcnt vmcnt(8)
// (tile t's 8 oldest loads done, t+1's stay in flight across the barrier), barrier,
// ds_read + 64 MFMA, lgkmcnt(0)+barrier (WAR release). No vmcnt(0) drain in the loop.
// LDS: 2 x (A 32KB + B 32KB) = 128 KiB -> 1 block/CU, 2 waves/SIMD.
// Swizzle (T2, both-sides): row of 8x16B chunks; LDS position p holds global chunk
// p ^ (row&7); staged via pre-swizzled GLOBAL source (LDS dest linear, m173 pattern);
// reads XOR the same -> 8 lanes per 4-bank group, all 32 banks busy, conflict-free.
template <int EPI>
__global__ __launch_bounds__(512, 2) void gemm256_kernel(const ushort* __restrict__ A,
    const ushort* __restrict__ Bw, const float* __restrict__ bias,
    void* __restrict__ outp, void* __restrict__ outp2, int K, int N, float scale) {
  __shared__ ushort As[2][256 * 64];   // 32 KB each buf
  __shared__ ushort Bs[2][256 * 64];
  const int t = threadIdx.x;
  const int lane = t & 63, wave = t >> 6;
  const int col = lane & 15, quad = lane >> 4;
  const int m0 = blockIdx.x * 256, n0 = blockIdx.y * 256;
  const int wm = wave >> 2, wn = wave & 3;   // 2 x 4 wave grid; per-wave out 128 x 64

  f32x4 acc[8][4];
  #pragma unroll
  for (int i = 0; i < 8; i++)
    #pragma unroll
    for (int j = 0; j < 4; j++)
      acc[i][j] = (f32x4){0.f, 0.f, 0.f, 0.f};

  // staging plan: 2048 16B-chunks per tile per operand; thread handles chunks
  // c = i*512 + t (i=0..3). row = c>>3, in-row pos p = c&7, global chunk = p^(row&7).
  size_t aoff[4], boff[4];
  int sdst[4];
  #pragma unroll
  for (int i = 0; i < 4; i++) {
    int c = i * 512 + t;
    int row = c >> 3, p = c & 7;
    int gcol = (p ^ (row & 7)) * 8;
    aoff[i] = (size_t)(m0 + row) * K + gcol;
    boff[i] = (size_t)(n0 + row) * K + gcol;
    sdst[i] = c * 8;   // ushort offset; = uniform base + lane*16B within each wave
  }

  const int NT = K >> 6;
  // prologue: stage tile 0 into buf 0
  #pragma unroll
  for (int i = 0; i < 4; i++) {
    async_cp16(A  + aoff[i], &As[0][sdst[i]]);
    async_cp16(Bw + boff[i], &Bs[0][sdst[i]]);
  }

  int cur = 0;
  for (int kt = 0; kt < NT; kt++) {
    if (kt + 1 < NT) {
      const int nxt = cur ^ 1;
      const int ko = (kt + 1) << 6;
      #pragma unroll
      for (int i = 0; i < 4; i++) {
        async_cp16(A  + aoff[i] + ko, &As[nxt][sdst[i]]);
        async_cp16(Bw + boff[i] + ko, &Bs[nxt][sdst[i]]);
      }
      asm volatile("s_waitcnt vmcnt(8)" ::: "memory");
    } else {
      asm volatile("s_waitcnt vmcnt(0)" ::: "memory");
    }
    __builtin_amdgcn_sched_barrier(0);
    __builtin_amdgcn_s_barrier();
    __builtin_amdgcn_sched_barrier(0);

    #pragma unroll
    for (int c = 0; c < 2; c++) {
      short8 af[8], bf[4];
      #pragma unroll
      for (int tm = 0; tm < 8; tm++) {
        const int row = wm * 128 + tm * 16 + col;
        af[tm] = *(const short8*)&As[cur][row * 64 + ((c * 4 + quad) ^ (row & 7)) * 8];
      }
      #pragma unroll
      for (int tn = 0; tn < 4; tn++) {
        const int row = wn * 64 + tn * 16 + col;
        bf[tn] = *(const short8*)&Bs[cur][row * 64 + ((c * 4 + quad) ^ (row & 7)) * 8];
      }
      __builtin_amdgcn_s_setprio(1);
      #pragma unroll
      for (int tm = 0; tm < 8; tm++)
        #pragma unroll
        for (int tn = 0; tn < 4; tn++)
          acc[tm][tn] = MFMA_BF16(af[tm], bf[tn], acc[tm][tn], 0, 0, 0);
      __builtin_amdgcn_s_setprio(0);
    }

    asm volatile("s_waitcnt lgkmcnt(0)" ::: "memory");
    __builtin_amdgcn_sched_barrier(0);
    __builtin_amdgcn_s_barrier();
    cur ^= 1;
  }

  #pragma unroll
  for (int tm = 0; tm < 8; tm++) {
    #pragma unroll
    for (int tn = 0; tn < 4; tn++) {
      const int n = n0 + wn * 64 + tn * 16 + col;
      const float bn = bias[n];
      #pragma unroll
      for (int r = 0; r < 4; r++) {
        const int m = m0 + wm * 128 + tm * 16 + quad * 4 + r;
        float v = acc[tm][tn][r] + bn;
        if (EPI == EPI_QK) {
          int nl = n & 1023, h = nl >> 6, hd = nl & 63;
          int bb = m >> 11, s2 = m & 2047;
          if (n < 1024)
            ((ushort*)outp)[(((size_t)(bb * 16 + h) * 2048 + s2) * 64) + hd] = f2bf(v * scale);
          else
            ((ushort*)outp2)[(((size_t)(bb * 16 + h) * 2048 + s2) * 64) + hd] = f2bf(v);
        } else {  // EPI_GELU
          float u = v * 0.7978845608028654f * (1.0f + 0.044715f * v * v);
          float e = __builtin_amdgcn_exp2f(u * 2.885390081777927f);  // e^{2u}
          float th = 1.0f - 2.0f * __builtin_amdgcn_rcpf(e + 1.0f);
          ((ushort*)outp)[(size_t)m * N + n] = f2bf(0.5f * v * (1.0f + th));
        }
      }
    }
  }
}

// ---------------- flash attention v9.1: conflict-free LDS + cvt_pk P-pack ----------
__global__ __launch_bounds__(256) void attn_kernel(const ushort* __restrict__ Qb,
    const ushort* __restrict__ Kb, const ushort* __restrict__ Vt,
    ushort* __restrict__ ctx) {
  const int lane = threadIdx.x & 63, wave = threadIdx.x >> 6;
  const int col = lane & 15, quad = lane >> 4;
  const int bx = blockIdx.x;
  const int bh = bx & 63;          // XCD = bh % 8 for every q-tile of this head
  const int qt = bx >> 6;          // 0..15
  const int qbase = qt * 128 + wave * 32;
  const ushort* Qh = Qb + (size_t)bh * 2048 * 64;
  const ushort* Kh = Kb + (size_t)bh * 2048 * 64;
  const ushort* Vh = Vt + (size_t)bh * 64 * 2048;

  short8 qa[2][2];
  #pragma unroll
  for (int qg = 0; qg < 2; qg++) {
    const ushort* Qr = Qh + (size_t)(qbase + qg * 16 + col) * 64 + quad * 8;
    qa[qg][0] = *(const short8*)Qr;
    qa[qg][1] = *(const short8*)(Qr + 32);
  }

  f32x4 Ot[2][4];
  float l_part[2];
  #pragma unroll
  for (int qg = 0; qg < 2; qg++) {
    l_part[qg] = 0.f;
    #pragma unroll
    for (int dt = 0; dt < 4; dt++) Ot[qg][dt] = (f32x4){0.f, 0.f, 0.f, 0.f};
  }

  __shared__ ushort Ks[2][2][64 * 32];     // [buf][d-half][key*32 + swz-chunk] 16 KB
  __shared__ ushort Vs[2][2][64 * 32];     // [buf][key-half][d*32 + swz-chunk] 16 KB
  __shared__ ushort P_lds[4][2][16][64];   // [wave][qg][q][8 x 16B chunks, swz] 16 KB

  const int lrow = lane >> 2;
  const int srow = wave * 16 + lrow;                       // row this lane stages
  const int lcol = ((lane & 3) ^ ((srow >> 1) & 3)) * 8;   // swizzled 16B chunk in 64B half
  const ushort* Kg = Kh + (size_t)srow * 64 + lcol;        // + kb*64 (+32 for half 1)
  const ushort* Vg = Vh + (size_t)srow * 2048 + lcol;      // + kb   (+32 for half 1)
  const int so = (wave * 16) * 32;

  const int kvswz = (col >> 1) & 3;   // fragment-read XOR (rows kt*16+col: (row>>1)&3)
  const int pswz = col & 7;           // P chunk XOR

  // prologue: stage chunk 0 into buf 0
  async_cp16(Kg,      &Ks[0][0][so]);
  async_cp16(Kg + 32, &Ks[0][1][so]);
  async_cp16(Vg,      &Vs[0][0][so]);
  async_cp16(Vg + 32, &Vs[0][1][so]);
  __syncthreads();

  int cur = 0;
  for (int kb = 0; kb < 2048; kb += 64) {
    if (kb + 64 < 2048) {
      const int nxt = cur ^ 1;
      async_cp16(Kg + (size_t)(kb + 64) * 64,      &Ks[nxt][0][so]);
      async_cp16(Kg + (size_t)(kb + 64) * 64 + 32, &Ks[nxt][1][so]);
      async_cp16(Vg + (kb + 64),                   &Vs[nxt][0][so]);
      async_cp16(Vg + (kb + 64) + 32,              &Vs[nxt][1][so]);
    }

    // fragments from LDS (shared across the 2 q-groups), swizzled reads
    short8 kf[4][2], vf[4][2];
    #pragma unroll
    for (int kt = 0; kt < 4; kt++)
      #pragma unroll
      for (int c = 0; c < 2; c++)
        kf[kt][c] = *(const short8*)&Ks[cur][c][(kt * 16 + col) * 32 + (quad ^ kvswz) * 8];
    #pragma unroll
    for (int dt = 0; dt < 4; dt++)
      #pragma unroll
      for (int c = 0; c < 2; c++)
        vf[dt][c] = *(const short8*)&Vs[cur][c][(dt * 16 + col) * 32 + (quad ^ kvswz) * 8];

    #pragma unroll
    for (int qg = 0; qg < 2; qg++) {
      f32x4 s[4];
      __builtin_amdgcn_s_setprio(1);
      #pragma unroll
      for (int kt = 0; kt < 4; kt++) {
        s[kt] = (f32x4){0.f, 0.f, 0.f, 0.f};
        s[kt] = MFMA_BF16(kf[kt][0], qa[qg][0], s[kt], 0, 0, 0);
        s[kt] = MFMA_BF16(kf[kt][1], qa[qg][1], s[kt], 0, 0, 0);
      }
      __builtin_amdgcn_s_setprio(0);
      ushort(*P)[64] = P_lds[wave][qg];
      #pragma unroll
      for (int kt = 0; kt < 4; kt++) {
        float p0 = __builtin_amdgcn_exp2f(s[kt][0]);
        float p1 = __builtin_amdgcn_exp2f(s[kt][1]);
        float p2 = __builtin_amdgcn_exp2f(s[kt][2]);
        float p3 = __builtin_amdgcn_exp2f(s[kt][3]);
        l_part[qg] += (p0 + p1) + (p2 + p3);
        uint2 pk;
        asm("v_cvt_pk_bf16_f32 %0, %1, %2" : "=v"(pk.x) : "v"(p0), "v"(p1));
        asm("v_cvt_pk_bf16_f32 %0, %1, %2" : "=v"(pk.y) : "v"(p2), "v"(p3));
        // keys kt*16+quad*4..+3 -> 16B chunk (2kt + quad>>1), half (quad&1); chunk ^= pswz
        *(uint2*)&P[col][(((2 * kt + (quad >> 1)) ^ pswz) * 8) + (quad & 1) * 4] = pk;
      }
    }
    #pragma unroll
    for (int qg = 0; qg < 2; qg++) {
      #pragma unroll
      for (int c = 0; c < 2; c++) {
        // keys c*32+quad*8..+7 -> chunk (4c+quad) ^ pswz
        short8 pf = *(const short8*)&P_lds[wave][qg][col][((4 * c + quad) ^ pswz) * 8];
        __builtin_amdgcn_s_setprio(1);
        #pragma unroll
        for (int dt = 0; dt < 4; dt++)
          Ot[qg][dt] = MFMA_BF16(vf[dt][c], pf, Ot[qg][dt], 0, 0, 0);
        __builtin_amdgcn_s_setprio(0);
      }
    }
    __syncthreads();
    cur ^= 1;
  }

  const int bb = bh >> 4, h = bh & 15;
  #pragma unroll
  for (int qg = 0; qg < 2; qg++) {
    float l = l_part[qg];
    l += __shfl_xor(l, 16);
    l += __shfl_xor(l, 32);
    float inv = __builtin_amdgcn_rcpf(l);
    const int q = qbase + qg * 16 + col;
    size_t base = ((size_t)(bb * 2048 + q)) * 1024 + h * 64;
    #pragma unroll
    for (int dt = 0; dt < 4; dt++) {
      ushort4 o;
      o.x = f2bf(Ot[qg][dt][0] * inv);
      o.y = f2bf(Ot[qg][dt][1] * inv);
      o.z = f2bf(Ot[qg][dt][2] * inv);
      o.w = f2bf(Ot[qg][dt][3] * inv);
      *(ushort4*)&ctx[base + dt * 16 + quad * 4] = o;
    }
  }
}

// ---------------- host ----------------
extern "C" void kernel_launch(void* const* d_in, const int* in_sizes, int n_in,
                              void* d_out, int out_size, void* d_ws, size_t ws_size,
                              hipStream_t stream) {
  const float* x     = (const float*)d_in[0];
  const float* Wq    = (const float*)d_in[1];
  const float* bq    = (const float*)d_in[2];
  const float* Wk    = (const float*)d_in[3];
  const float* bk    = (const float*)d_in[4];
  const float* Wv    = (const float*)d_in[5];
  const float* bv    = (const float*)d_in[6];
  const float* Wo    = (const float*)d_in[7];
  const float* bo    = (const float*)d_in[8];
  const float* W1    = (const float*)d_in[9];
  const float* b1    = (const float*)d_in[10];
  const float* W2    = (const float*)d_in[11];
  const float* b2    = (const float*)d_in[12];
  const float* ln1_g = (const float*)d_in[13];
  const float* ln1_b = (const float*)d_in[14];
  const float* ln2_g = (const float*)d_in[15];
  const float* ln2_b = (const float*)d_in[16];

  const size_t MB = 1ull << 20;
  char* ws = (char*)d_ws;
  ushort* Wqkv_b = (ushort*)(ws + 0 * MB);    // 6 MB  [3072,1024] (Q|K|V)
  ushort* Wo_b   = (ushort*)(ws + 6 * MB);    // 2 MB
  ushort* W1_b   = (ushort*)(ws + 8 * MB);    // 8 MB
  ushort* W2_b   = (ushort*)(ws + 16 * MB);   // 8 MB
  ushort* xn1    = (ushort*)(ws + 24 * MB);   // 16 MB
  ushort* Qb     = (ushort*)(ws + 40 * MB);   // 16 MB
  ushort* Kb     = (ushort*)(ws + 56 * MB);   // 16 MB
  ushort* Vt     = (ushort*)(ws + 72 * MB);   // 16 MB
  ushort* ctxb   = (ushort*)(ws + 88 * MB);   // 16 MB
  float*  x2     = (float*)(ws + 104 * MB);   // 32 MB
  ushort* xn2    = (ushort*)(ws + 136 * MB);  // 16 MB
  ushort* y1     = (ushort*)(ws + 152 * MB);  // 64 MB -> end 216 MB
  // bqkv aliases start of y1 (lifetime-disjoint: consumed before GELU GEMM writes y1)
  float*  bqkv   = (float*)(ws + 152 * MB);

  conv_all<<<12291, 256, 0, stream>>>(Wq, Wk, Wv, Wo, W1, W2, bq, bk, bv,
                                      Wqkv_b, Wo_b, W1_b, W2_b, bqkv);

  ln_kernel<<<8192, 256, 0, stream>>>(x, ln1_g, ln1_b, xn1);

  const float cs = 0.125f * 1.4426950408889634f;  // log2(e)/sqrt(64), folded into Q
  // Q|K projections (N=2048): 256^2 counted-vmcnt kernel
  gemm256_kernel<EPI_QK><<<dim3(32, 8), 512, 0, stream>>>(
      xn1, Wqkv_b, bqkv, Qb, Kb, 1024, 2048, cs);
  // V^T projection: A = Wv (rows = v-dim), B = xn (rows = tokens) -> C[vdim, token]
  gemm_kernel<EPI_VT><<<dim3(8, 64), 256, 0, stream>>>(
      Wqkv_b + (size_t)2048 * 1024, xn1, bqkv + 2048, nullptr, Vt, nullptr,
      1024, 8192, 1.0f);

  attn_kernel<<<1024, 256, 0, stream>>>(Qb, Kb, Vt, ctxb);

  gemm_kernel<EPI_WO><<<dim3(64, 8), 256, 0, stream>>>(
      ctxb, Wo_b, bo, x, x2, nullptr, 1024, 1024, 1.0f);

  ln_kernel<<<8192, 256, 0, stream>>>(x2, ln2_g, ln2_b, xn2);

  gemm256_kernel<EPI_GELU><<<dim3(32, 16), 512, 0, stream>>>(
      xn2, W1_b, b1, y1, nullptr, 1024, 4096, 1.0f);
  gemm_kernel<EPI_OUT><<<dim3(64, 8), 256, 0, stream>>>(
      y1, W2_b, b2, x2, d_out, nullptr, 4096, 1024, 1.0f);
}